// Round 10
// baseline (94.595 us; speedup 1.0000x reference)
//
#include <hip/hip_runtime.h>
#include <hip/hip_bf16.h>
#include <stdint.h>

// Problem constants: B=4, L=2048, D=1024, vocab<32, N_GRAM=3
#define LSEQ 2048
#define DDIM 1024

typedef __attribute__((ext_vector_type(8))) short bf16x8;
typedef __attribute__((ext_vector_type(16))) float f32x16;

__device__ __forceinline__ ushort f2bf(float x) {
    uint32_t u = __builtin_bit_cast(uint32_t, x);
    u += 0x7fffu + ((u >> 16) & 1u);   // RNE (inputs finite/normal)
    return (ushort)(u >> 16);
}

__device__ __forceinline__ void stage16(const void* g, void* lds) {
    __builtin_amdgcn_global_load_lds((const __attribute__((address_space(1))) void*)g,
                                     (__attribute__((address_space(3))) void*)lds, 16, 0, 0);
}

// 8B-granular swizzle in a row-major bf16 buffer, 2048B row stride.
// Within each 128B k-block: 16 slots of 8B; slot8 = ((k>>2)&15) ^ (row&15).
// Baked into global layout by producers (rule 21: glds stays linear); readers XOR.
// Bank proof: a frag read is ds_read_b64 at slot (j16*2)^(l31&15) — per 16-lane
// phase all 16 slots distinct -> 1 access/bank/phase (perfect spread).
__device__ __forceinline__ int swz8(int row, int k) {
    return row * 2048 + ((k >> 6) << 7) + ((((k >> 2) & 15) ^ (row & 15)) << 3) + ((k & 3) << 1);
}

// ------- Kernel 1 (fused prep): pooled + W-transpose + H->bf16 -------------------
// blocks [0,8192): pooled rows (longest-first remap); [8192,8704): W; [8704,9728): H.
__global__ __launch_bounds__(256) void prep(const float* __restrict__ H,
                                            const int* __restrict__ ids,
                                            const float* __restrict__ W1,
                                            const float* __restrict__ W2,
                                            char* __restrict__ Hb,
                                            char* __restrict__ Pb,
                                            char* __restrict__ W1t,
                                            char* __restrict__ W2t) {
    int bid = blockIdx.x;
    int tid = threadIdx.x;
    if (bid < 8192) {
        // longest-scan-first: i descends with bid within each batch row
        int b = bid >> 11;
        int i = (LSEQ - 1) - (bid & (LSEQ - 1));
        int base = b * LSEQ;
        int row = base + i;

        __shared__ int sids[LSEQ];    // 8KB
        __shared__ int skey[LSEQ];    // 8KB
        __shared__ unsigned bm[8];
        for (int c = tid; c < LSEQ; c += 256) sids[c] = ids[base + c];
        __syncthreads();
        for (int c = tid; c < LSEQ; c += 256)
            skey[c] = c >= 2 ? ((sids[c - 2] << 10) | (sids[c - 1] << 5) | sids[c]) : 0;
        __syncthreads();

        int key_i = skey[i];
        const float4* H4 = (const float4*)H;
        float4 acc = make_float4(0.f, 0.f, 0.f, 0.f);
        int count = 0;
        for (int j0 = 0; j0 < i; j0 += 256) {
            if (tid < 8) bm[tid] = 0u;
            __syncthreads();
            int j = j0 + tid;
            if (j < i && skey[j] == key_i)
                atomicOr(&bm[tid >> 5], 1u << (tid & 31));
            __syncthreads();
            #pragma unroll
            for (int w = 0; w < 8; ++w) {
                unsigned m = bm[w];
                while (m) {
                    int bit = __ffs(m) - 1;
                    m &= m - 1;
                    int j2 = j0 + w * 32 + bit;
                    count++;
                    float4 h = H4[(size_t)(base + j2) * (DDIM / 4) + tid];
                    acc.x += h.x; acc.y += h.y; acc.z += h.z; acc.w += h.w;
                }
            }
            __syncthreads();
        }
        float s = 1.0f / (float)(count > 0 ? count : 1);
        ushort4 o;
        o.x = f2bf(acc.x * s); o.y = f2bf(acc.y * s);
        o.z = f2bf(acc.z * s); o.w = f2bf(acc.w * s);
        *(ushort4*)(Pb + swz8(row, tid * 4)) = o;    // 8B-aligned slot write
    } else if (bid < 8704) {
        // W[K][N] fp32 -> Wt[N][K] bf16, swizzle-baked. 512 blocks: 16(k) x 16(n) x 2
        int b2 = bid - 8192;
        const float* W = (b2 >> 8) ? W2 : W1;
        char* Wt = (b2 >> 8) ? W2t : W1t;
        int r2 = b2 & 255;
        int k0 = (r2 & 15) * 64, n0 = (r2 >> 4) * 64;
        __shared__ ushort t[64][65];
        #pragma unroll
        for (int it = 0; it < 16; ++it) {
            int idx = it * 256 + tid;
            int r = idx >> 6, c = idx & 63;
            t[c][r] = f2bf(W[(size_t)(k0 + r) * DDIM + n0 + c]);
        }
        __syncthreads();
        #pragma unroll
        for (int it = 0; it < 4; ++it) {
            int idx = it * 256 + tid;
            int r = idx >> 4, g = idx & 15;
            ushort4 v;
            v.x = t[r][g * 4]; v.y = t[r][g * 4 + 1];
            v.z = t[r][g * 4 + 2]; v.w = t[r][g * 4 + 3];
            *(ushort4*)(Wt + swz8(n0 + r, k0 + g * 4)) = v;
        }
    } else {
        // H fp32 -> Hb bf16, swizzle-baked. 1024 blocks x 8 rows.
        int r0 = (bid - 8704) * 8;
        #pragma unroll
        for (int rr = 0; rr < 8; ++rr) {
            int row = r0 + rr;
            float4 h = *(const float4*)(H + (size_t)row * DDIM + tid * 4);
            ushort4 o;
            o.x = f2bf(h.x); o.y = f2bf(h.y); o.z = f2bf(h.z); o.w = f2bf(h.w);
            *(ushort4*)(Hb + swz8(row, tid * 4)) = o;
        }
    }
}

// ---------------- Kernel 2: out = H@W1 + P@W2 + (b1+b2), 32x32x16 bf16 MFMA -------
// Tile 256(M)x128(N), BK=64, 8 waves (4Mx2N), wave tile 64x64. Grid 256 = 1/CU.
// Uniform all-glds loop (Hb steps 0-15, Pb 16-31), triple-buffered LDS, depth-2
// prefetch, counted vmcnt(6) (never 0 in-loop). Frag reads = ds_read_b64 pairs
// with 4-bit XOR slots -> bank-conflict-free per 16-lane phase.
__global__ __launch_bounds__(512, 2) void gemm_bf16(
    const char* __restrict__ Hb,      // bf16 swizzle-baked
    const char* __restrict__ Pb,
    const char* __restrict__ W1t,
    const char* __restrict__ W2t,
    const float* __restrict__ b1,
    const float* __restrict__ b2,
    float* __restrict__ out)
{
    __shared__ __align__(128) char AsBuf[3][32768];   // [256 rows][128B]
    __shared__ __align__(128) char BsBuf[3][16384];   // [128 rows][128B]

    const int tid = threadIdx.x;
    const int lane = tid & 63;
    const int wid = tid >> 6;
    const int wr = wid >> 1, wc = wid & 1;
    const int l31 = lane & 31;
    const int hi2 = lane >> 5;
    const int xk = l31 & 15;

    // XCD-aware mapping (R5-proven): xcd = bid&7 owns 4 row-tiles x 8 col-tiles
    const int bid = blockIdx.x;
    const int j = bid >> 3;
    const int row0 = ((bid & 7) * 4 + (j >> 3)) * 256;
    const int col0 = (j & 7) * 128;

    f32x16 acc[2][2];
    #pragma unroll
    for (int mm = 0; mm < 2; ++mm)
        #pragma unroll
        for (int nn = 0; nn < 2; ++nn)
            #pragma unroll
            for (int q = 0; q < 16; ++q) acc[mm][nn][q] = 0.f;

    const int o_lin = wid * 1024 + lane * 16;
    const int srow = o_lin >> 7;
    const int sbyte = o_lin & 127;

    char* Acur = &AsBuf[0][0]; char* Anx1 = &AsBuf[1][0]; char* Anx2 = &AsBuf[2][0];
    char* Bcur = &BsBuf[0][0]; char* Bnx1 = &BsBuf[1][0]; char* Bnx2 = &BsBuf[2][0];

    auto stageB = [&](char* dstB, const char* W, int kb) {
        #pragma unroll
        for (int c = 0; c < 2; ++c)
            stage16(W + (size_t)(col0 + c * 64 + srow) * 2048 + kb + sbyte,
                    dstB + c * 8192 + wid * 1024);
    };
    auto stageA = [&](char* dstA, const char* Ab, int kb) {
        #pragma unroll
        for (int c = 0; c < 4; ++c)
            stage16(Ab + (size_t)(row0 + c * 64 + srow) * 2048 + kb + sbyte,
                    dstA + c * 8192 + wid * 1024);
    };
    auto comb = [](short4 a, short4 b) {
        bf16x8 r;
        r[0] = a.x; r[1] = a.y; r[2] = a.z; r[3] = a.w;
        r[4] = b.x; r[5] = b.y; r[6] = b.z; r[7] = b.w;
        return r;
    };
    auto compute = [&]() {
        bf16x8 af[2][4], bf[2][4];
        #pragma unroll
        for (int ks = 0; ks < 4; ++ks) {
            const int p0 = (((ks * 2 + hi2) * 2) ^ xk) << 3;   // 8B slot; pair at p0^8
            #pragma unroll
            for (int mm = 0; mm < 2; ++mm) {
                const char* base = Acur + (wr * 64 + mm * 32 + l31) * 128;
                af[mm][ks] = comb(*(const short4*)(base + p0),
                                  *(const short4*)(base + (p0 ^ 8)));
            }
            #pragma unroll
            for (int nn = 0; nn < 2; ++nn) {
                const char* base = Bcur + (wc * 64 + nn * 32 + l31) * 128;
                bf[nn][ks] = comb(*(const short4*)(base + p0),
                                  *(const short4*)(base + (p0 ^ 8)));
            }
        }
        __builtin_amdgcn_s_setprio(1);
        #pragma unroll
        for (int ks = 0; ks < 4; ++ks)
            #pragma unroll
            for (int mm = 0; mm < 2; ++mm)
                #pragma unroll
                for (int nn = 0; nn < 2; ++nn)
                    acc[mm][nn] = __builtin_amdgcn_mfma_f32_32x32x16_bf16(
                        af[mm][ks], bf[nn][ks], acc[mm][nn], 0, 0, 0);
        __builtin_amdgcn_s_setprio(0);
    };
    auto rotate = [&]() {
        char* tp;
        tp = Acur; Acur = Anx1; Anx1 = Anx2; Anx2 = tp;
        tp = Bcur; Bcur = Bnx1; Bnx1 = Bnx2; Bnx2 = tp;
    };

    // prologue: stage tiles 0,1
    stageA(Acur, Hb, 0);        stageB(Bcur, W1t, 0);
    stageA(Anx1, Hb, 1 << 7);   stageB(Bnx1, W1t, 1 << 7);
    asm volatile("s_waitcnt vmcnt(6)" ::: "memory");    // tile 0 staged
    __builtin_amdgcn_s_barrier();

    #pragma unroll 1
    for (int t = 0; t < 30; ++t) {
        const int t2 = t + 2;
        const char* Ab = t2 < 16 ? Hb : Pb;
        const char* Wb = t2 < 16 ? W1t : W2t;
        const int kb = (t2 & 15) << 7;
        stageA(Anx2, Ab, kb);
        stageB(Bnx2, Wb, kb);
        compute();
        asm volatile("s_waitcnt vmcnt(6)" ::: "memory");  // t+1 staged; t+2 in flight
        __builtin_amdgcn_s_barrier();
        rotate();
    }
    compute();
    asm volatile("s_waitcnt vmcnt(0)" ::: "memory");
    __builtin_amdgcn_s_barrier();
    rotate();
    compute();

    // epilogue: 32x32 C/D layout col=lane&31, row=(reg&3)+8*(reg>>2)+4*(lane>>5)
    #pragma unroll
    for (int mm = 0; mm < 2; ++mm) {
        #pragma unroll
        for (int nn = 0; nn < 2; ++nn) {
            const int c = col0 + wc * 64 + nn * 32 + l31;
            const float bias = b1[c] + b2[c];
            const int rbase = row0 + wr * 64 + mm * 32 + hi2 * 4;
            #pragma unroll
            for (int reg = 0; reg < 16; ++reg) {
                int r = rbase + (reg & 3) + 8 * (reg >> 2);
                out[(size_t)r * DDIM + c] = acc[mm][nn][reg] + bias;
            }
        }
    }
}

extern "C" void kernel_launch(void* const* d_in, const int* in_sizes, int n_in,
                              void* d_out, int out_size, void* d_ws, size_t ws_size,
                              hipStream_t stream) {
    const float* H  = (const float*)d_in[0];
    const int*   ids = (const int*)d_in[1];
    const float* W1 = (const float*)d_in[2];
    const float* b1 = (const float*)d_in[3];
    const float* W2 = (const float*)d_in[4];
    const float* b2 = (const float*)d_in[5];
    float* out = (float*)d_out;

    char* ws = (char*)d_ws;
    // Hb 16MB | Pb 16MB | W1t 2MB | W2t 2MB = 36MB (R9 proved this fits)
    char* Hb  = ws;
    char* Pb  = ws + (16 << 20);
    char* W1t = ws + (32 << 20);
    char* W2t = ws + (34 << 20);

    prep<<<9728, 256, 0, stream>>>(H, ids, W1, W2, Hb, Pb, W1t, W2t);
    gemm_bf16<<<256, 512, 0, stream>>>(Hb, Pb, W1t, W2t, b1, b2, out);
}